// Round 6
// baseline (260.476 us; speedup 1.0000x reference)
//
#include <hip/hip_runtime.h>

typedef __attribute__((ext_vector_type(8))) short s16x8;
typedef __attribute__((ext_vector_type(4))) float f32x4;
typedef unsigned int u32;

#define CCH 128

__device__ __forceinline__ ushort f2bf(float f) {
  uint u = __float_as_uint(f);
  u += 0x7fffu + ((u >> 16) & 1u);
  return (ushort)(u >> 16);
}
__device__ __forceinline__ float bf2f(ushort u) {
  return __uint_as_float(((uint)u) << 16);
}

// swizzled element index into a [row][128] bf16 tile (8-elem granule XOR)
__device__ __forceinline__ int swz(int row, int col) {
  return (row << 7) | (col ^ ((row & 7) << 3));
}

__device__ __forceinline__ void gll16(const void* g, void* l) {
  __builtin_amdgcn_global_load_lds((const __attribute__((address_space(1))) u32*)g,
                                   (__attribute__((address_space(3))) u32*)l, 16, 0, 0);
}

// ---------------- pass1: stats + NCHW fp32 -> pre-swizzled bf16 tile images ----------------
// 4096 blocks (XCD-swizzled: XCD k <-> batch k), 256 thr, 32 KiB LDS, 128-px tiles.
__global__ __launch_bounds__(256) void pass1(const float* __restrict__ x,
                                             ushort* __restrict__ xb,
                                             float2* __restrict__ partials) {
  __shared__ ushort sT[128 * CCH];  // 32 KiB, internal granule4 swizzle
  __shared__ float wsa[4][4], wsb[4][4];
  const int t = threadIdx.x;
  const int blk = ((blockIdx.x & 7) << 9) | (blockIdx.x >> 3);  // bijective
  const int b = blk >> 9;
  const int p0 = (blk & 511) << 7;
  const int wv = t >> 6, lane = t & 63;
  const int px4 = (t & 31) * 4;
  const int c8 = t >> 5;  // 0..7

  float sa[4], sq[4];
#pragma unroll
  for (int i = 0; i < 4; ++i) { sa[i] = 0.f; sq[i] = 0.f; }

  const float* xbase = x + (((size_t)b * CCH) << 16) + p0;
#pragma unroll
  for (int i = 0; i < 4; ++i) {
    const int ch = i * 32 + c8 * 4;
    float4 v[4];
#pragma unroll
    for (int j = 0; j < 4; ++j)
      v[j] = *(const float4*)(xbase + (((size_t)(ch + j)) << 16) + px4);
#pragma unroll
    for (int j = 0; j < 4; ++j) {
      sa[i] += v[j].x + v[j].y + v[j].z + v[j].w;
      sq[i] += v[j].x * v[j].x + v[j].y * v[j].y + v[j].z * v[j].z + v[j].w * v[j].w;
    }
    const int c4 = i * 8 + c8;
#pragma unroll
    for (int k = 0; k < 4; ++k) {
      const int row = px4 + k;
      const int gs = c4 ^ (((row >> 3) & 15) << 1);
      ushort4 pk;
      pk.x = f2bf(((const float*)&v[0])[k]);
      pk.y = f2bf(((const float*)&v[1])[k]);
      pk.z = f2bf(((const float*)&v[2])[k]);
      pk.w = f2bf(((const float*)&v[3])[k]);
      *(ushort4*)&sT[row * CCH + gs * 4] = pk;
    }
  }
  // per-wave group accumulator i belongs to group g = 2*i + (wv>>1)
#pragma unroll
  for (int i = 0; i < 4; ++i) {
    float a = sa[i], q = sq[i];
#pragma unroll
    for (int off = 32; off > 0; off >>= 1) {
      a += __shfl_down(a, off);
      q += __shfl_down(q, off);
    }
    if (lane == 0) { wsa[wv][i] = a; wsb[wv][i] = q; }
  }
  __syncthreads();
  if (t < 8) {
    const int g = t;
    const int w0 = (g & 1) * 2, ii = g >> 1;
    partials[blk * 8 + g] =
        (float2){wsa[w0][ii] + wsa[w0 + 1][ii], wsb[w0][ii] + wsb[w0 + 1][ii]};
  }
  // phase B: emit the pre-swizzled 32 KiB tile image (1 KiB contiguous per wave inst)
  const int g = t & 15, pr = t >> 4;
  ushort* dst = xb + ((size_t)blk << 14);
#pragma unroll
  for (int s = 0; s < 8; ++s) {
    const int row = s * 16 + pr;
    const int sidx = row * CCH + (((2 * g) ^ (((row >> 3) & 15) << 1)) * 4);
    const int didx = row * CCH + ((g ^ (row & 7)) * 8);
    *(s16x8*)&dst[didx] = *(const s16x8*)&sT[sidx];
  }
}

// ---------------- finalize + weight prep ----------------
__global__ void stats_finalize2(const float2* __restrict__ partials,
                                const float* __restrict__ gn_w,
                                const float* __restrict__ gn_b,
                                float* __restrict__ scale, float* __restrict__ shift) {
  const int t = threadIdx.x;
  const int b = t >> 3, g = t & 7;
  float s1 = 0.f, s2 = 0.f;
  for (int c = 0; c < 512; ++c) {
    float2 p = partials[(b * 512 + c) * 8 + g];
    s1 += p.x;
    s2 += p.y;
  }
  const float invN = 1.0f / 1048576.0f;
  const float mean = s1 * invN;
  const float var = s2 * invN - mean * mean;
  const float rstd = rsqrtf(var + 1e-5f);
  for (int i = 0; i < 16; ++i) {
    const int c = g * 16 + i;
    const float sc = rstd * gn_w[c];
    scale[b * CCH + c] = sc;
    shift[b * CCH + c] = gn_b[c] - mean * sc;
  }
}

__global__ __launch_bounds__(256) void prep_w2(const float* __restrict__ w2,
                                               ushort* __restrict__ w2b) {
  int i = blockIdx.x * 256 + threadIdx.x;
  float4 a = ((const float4*)w2)[i];
  ushort4 o;
  o.x = f2bf(a.x); o.y = f2bf(a.y); o.z = f2bf(a.z); o.w = f2bf(a.w);
  ((ushort4*)w2b)[i] = o;
}

__global__ __launch_bounds__(128) void fold_w1(const float* __restrict__ w1,
                                               const float* __restrict__ b1,
                                               const float* __restrict__ scale,
                                               const float* __restrict__ shift,
                                               ushort* __restrict__ W1b,
                                               float* __restrict__ c1) {
  const int b = blockIdx.x >> 7, o = blockIdx.x & 127, c = threadIdx.x;
  const float wv = w1[o * CCH + c];
  W1b[(b << 14) + o * CCH + c] = f2bf(wv * scale[b * CCH + c]);
  float s = wv * shift[b * CCH + c];
#pragma unroll
  for (int off = 32; off > 0; off >>= 1) s += __shfl_down(s, off);
  __shared__ float tmp[2];
  if ((threadIdx.x & 63) == 0) tmp[threadIdx.x >> 6] = s;
  __syncthreads();
  if (threadIdx.x == 0) c1[(b << 7) + o] = tmp[0] + tmp[1] + b1[o];
}

// ---------------- pass2: persistent 2-deep pipelined MLP ----------------
// 512 blocks (2/CU, XCD k <-> batch k), 8 tiles each, 2 x 32 KiB LDS double buffer.
#define NT 8
__global__ __launch_bounds__(256) void mlp_pipe(
    const ushort* __restrict__ xb, const ushort* __restrict__ W1b,
    const ushort* __restrict__ w2b, const float* __restrict__ c1,
    const float* __restrict__ b2, float* __restrict__ out) {
  __shared__ ushort sB[2][128 * CCH];  // 64 KiB
  const int t = threadIdx.x, lane = t & 63, wv = t >> 6;
  const int fl = lane & 15, fh = lane >> 4;
  const int blk = ((blockIdx.x & 7) << 6) | (blockIdx.x >> 3);  // bijective
  const int gt0 = blk * NT;
  const int b = gt0 >> 9;
  const ushort* w1p = W1b + (b << 14);
  const float* c1b = c1 + (b << 7);

  // prologue: stage tile 0 into buf 0
  {
    const char* s0 = (const char*)xb + ((size_t)gt0 << 15) + wv * 8192 + lane * 16;
    ushort* l0 = &sB[0][wv * 4096];
#pragma unroll
    for (int i = 0; i < 8; ++i) gll16(s0 + i * 1024, l0 + i * 512);
  }

#pragma unroll 1
  for (int it = 0; it < NT; ++it) {
    const int cur = it & 1;
    const int gt = gt0 + it;
    if (it + 1 < NT) {  // issue next-tile prefetch, keep it in flight (T4)
      const char* s0 = (const char*)xb + ((size_t)(gt + 1) << 15) + wv * 8192 + lane * 16;
      ushort* l0 = &sB[cur ^ 1][wv * 4096];
#pragma unroll
      for (int i = 0; i < 8; ++i) gll16(s0 + i * 1024, l0 + i * 512);
      __builtin_amdgcn_sched_barrier(0);
      asm volatile("s_waitcnt vmcnt(8)" ::: "memory");
    } else {
      asm volatile("s_waitcnt vmcnt(0)" ::: "memory");
    }
    __builtin_amdgcn_sched_barrier(0);
    __builtin_amdgcn_s_barrier();  // B1: buf[cur] = xn tile ready
    __builtin_amdgcn_sched_barrier(0);

    ushort* sb = &sB[cur][0];

    // ---- GEMM1: H = W1' . x ----
    f32x4 acc[2][8];
#pragma unroll
    for (int f = 0; f < 2; ++f)
#pragma unroll
      for (int j = 0; j < 8; ++j) acc[f][j] = (f32x4){0.f, 0.f, 0.f, 0.f};
#pragma unroll
    for (int k0 = 0; k0 < 128; k0 += 32) {
      const int kb = k0 + fh * 8;
      const s16x8 a0 = *(const s16x8*)(w1p + (wv * 32 + fl) * CCH + kb);
      const s16x8 a1 = *(const s16x8*)(w1p + (wv * 32 + 16 + fl) * CCH + kb);
#pragma unroll
      for (int j = 0; j < 8; ++j) {
        const s16x8 bf = *(const s16x8*)&sb[swz(j * 16 + fl, kb)];
        acc[0][j] = __builtin_amdgcn_mfma_f32_16x16x32_bf16(a0, bf, acc[0][j], 0, 0, 0);
        acc[1][j] = __builtin_amdgcn_mfma_f32_16x16x32_bf16(a1, bf, acc[1][j], 0, 0, 0);
      }
    }
    asm volatile("s_waitcnt lgkmcnt(0)" ::: "memory");
    __builtin_amdgcn_sched_barrier(0);
    __builtin_amdgcn_s_barrier();  // B2: all waves done reading xn
    __builtin_amdgcn_sched_barrier(0);

    // ---- wb: capture residual to regs, overwrite with H = relu(acc + c1) ----
    ushort4 rx[2][8];
#pragma unroll
    for (int f = 0; f < 2; ++f) {
      const int ob = wv * 32 + f * 16 + fh * 4;
      const float4 cc = *(const float4*)(c1b + ob);
#pragma unroll
      for (int j = 0; j < 8; ++j) {
        ushort* p = &sb[swz(j * 16 + fl, ob)];
        rx[f][j] = *(const ushort4*)p;  // residual (read before overwrite, same thread)
        ushort4 pk;
        pk.x = f2bf(fmaxf(acc[f][j][0] + cc.x, 0.f));
        pk.y = f2bf(fmaxf(acc[f][j][1] + cc.y, 0.f));
        pk.z = f2bf(fmaxf(acc[f][j][2] + cc.z, 0.f));
        pk.w = f2bf(fmaxf(acc[f][j][3] + cc.w, 0.f));
        *(ushort4*)p = pk;
      }
    }
    asm volatile("s_waitcnt lgkmcnt(0)" ::: "memory");
    __builtin_amdgcn_sched_barrier(0);
    __builtin_amdgcn_s_barrier();  // B3: H ready
    __builtin_amdgcn_sched_barrier(0);

    // ---- GEMM2: ffn = w2 . H ----
    f32x4 acc2[2][8];
#pragma unroll
    for (int f = 0; f < 2; ++f)
#pragma unroll
      for (int j = 0; j < 8; ++j) acc2[f][j] = (f32x4){0.f, 0.f, 0.f, 0.f};
#pragma unroll
    for (int k0 = 0; k0 < 128; k0 += 32) {
      const int kb = k0 + fh * 8;
      const s16x8 a0 = *(const s16x8*)(w2b + (wv * 32 + fl) * CCH + kb);
      const s16x8 a1 = *(const s16x8*)(w2b + (wv * 32 + 16 + fl) * CCH + kb);
#pragma unroll
      for (int j = 0; j < 8; ++j) {
        const s16x8 bf = *(const s16x8*)&sb[swz(j * 16 + fl, kb)];
        acc2[0][j] = __builtin_amdgcn_mfma_f32_16x16x32_bf16(a0, bf, acc2[0][j], 0, 0, 0);
        acc2[1][j] = __builtin_amdgcn_mfma_f32_16x16x32_bf16(a1, bf, acc2[1][j], 0, 0, 0);
      }
    }
    asm volatile("s_waitcnt lgkmcnt(0)" ::: "memory");
    __builtin_amdgcn_sched_barrier(0);
    __builtin_amdgcn_s_barrier();  // B4: H reads done -> sb reusable as fp32 tile
    __builtin_amdgcn_sched_barrier(0);

    // ---- epilogue: out = x + ffn + b2 via LDS transpose -> 512B contiguous stores ----
    float* sF = (float*)sb;
    const int p0 = (gt & 511) << 7;
    const int rowbase = wv * 16;
#pragma unroll
    for (int f = 0; f < 2; ++f) {
      const int ob = wv * 32 + f * 16 + fh * 4;
      const float4 bb = *(const float4*)(b2 + ob);
#pragma unroll
      for (int j = 0; j < 8; ++j) {
        const int rb = (rowbase + fh * 4) * 128 + j * 16 + fl;
        sF[rb]       = acc2[f][j][0] + bb.x + bf2f(rx[f][j].x);
        sF[rb + 128] = acc2[f][j][1] + bb.y + bf2f(rx[f][j].y);
        sF[rb + 256] = acc2[f][j][2] + bb.z + bf2f(rx[f][j].z);
        sF[rb + 384] = acc2[f][j][3] + bb.w + bf2f(rx[f][j].w);
      }
#pragma unroll
      for (int i = 0; i < 16; ++i) {
        const float2 v = *(const float2*)&sF[(rowbase + i) * 128 + lane * 2];
        const int ch = wv * 32 + f * 16 + i;
        *(float2*)(out + (((size_t)(b * CCH + ch)) << 16) + p0 + lane * 2) = v;
      }
    }
    asm volatile("s_waitcnt lgkmcnt(0)" ::: "memory");
    __builtin_amdgcn_sched_barrier(0);
    __builtin_amdgcn_s_barrier();  // B5: epilogue LDS done -> next prefetch may write buf
    __builtin_amdgcn_sched_barrier(0);
  }
}

// ---------------- launcher ----------------
extern "C" void kernel_launch(void* const* d_in, const int* in_sizes, int n_in,
                              void* d_out, int out_size, void* d_ws, size_t ws_size,
                              hipStream_t stream) {
  const float* x    = (const float*)d_in[0];
  const float* gn_w = (const float*)d_in[1];
  const float* gn_b = (const float*)d_in[2];
  const float* w1   = (const float*)d_in[3];
  const float* b1   = (const float*)d_in[4];
  const float* w2   = (const float*)d_in[5];
  const float* b2   = (const float*)d_in[6];
  float* out = (float*)d_out;
  char* ws = (char*)d_ws;

  const size_t XB = (size_t)8 * 65536 * CCH * 2;  // 128 MiB pre-swizzled tiles
  ushort* xbuf  = (ushort*)ws;
  float2* parts = (float2*)(ws + XB);             // 256 KiB (aliased by W1b later)
  ushort* W1b   = (ushort*)(ws + XB);             // 256 KiB (after finalize consumed parts)
  float* scale  = (float*)(ws + XB + 262144);
  float* shift  = (float*)(ws + XB + 266240);
  ushort* w2b   = (ushort*)(ws + XB + 270336);
  float* c1     = (float*)(ws + XB + 303104);

  hipLaunchKernelGGL(pass1, dim3(4096), dim3(256), 0, stream, x, xbuf, parts);
  hipLaunchKernelGGL(stats_finalize2, dim3(1), dim3(64), 0, stream, parts, gn_w, gn_b, scale, shift);
  hipLaunchKernelGGL(fold_w1, dim3(1024), dim3(128), 0, stream, w1, b1, scale, shift, W1b, c1);
  hipLaunchKernelGGL(prep_w2, dim3(16), dim3(256), 0, stream, w2, w2b);
  hipLaunchKernelGGL(mlp_pipe, dim3(512), dim3(256), 0, stream, xbuf, W1b, w2b, c1, b2, out);
}